// Round 2
// baseline (917.765 us; speedup 1.0000x reference)
//
#include <hip/hip_runtime.h>
#include <math.h>

#define N_NODES 1000000
#define DIM 128
#define TOPK 16
#define BLOCKS1 1024
#define THREADS 256
#define NCAND (BLOCKS1 * TOPK)

typedef float f32x4 __attribute__((ext_vector_type(4)));

__device__ __forceinline__ bool lexless(float v1, int i1, float v2, int i2) {
    return (v1 < v2) || (v1 == v2 && i1 < i2);
}

// Insert (v,i) into ascending top-16 list held entirely in registers.
// Fully unrolled: all indices compile-time constant (no scratch spill).
__device__ __forceinline__ void insert16(float (&bv)[TOPK], int (&bi)[TOPK],
                                         float v, int i) {
    if (!lexless(v, i, bv[TOPK - 1], bi[TOPK - 1])) return;
#pragma unroll
    for (int j = TOPK - 1; j > 0; --j) {
        if (lexless(v, i, bv[j - 1], bi[j - 1])) {
            bv[j] = bv[j - 1]; bi[j] = bi[j - 1];
        } else {
            bv[j] = v; bi[j] = i;
            return;
        }
    }
    bv[0] = v; bi[0] = i;
}

__device__ __forceinline__ float rowdist2(f32x4 x, f32x4 s) {
    float d = x.x - s.x; float a = d * d;
    d = x.y - s.y; a = fmaf(d, d, a);
    d = x.z - s.z; a = fmaf(d, d, a);
    d = x.w - s.w; a = fmaf(d, d, a);
    return a;
}

// Stage 1: distances + per-block top-16.
// Each 32-lane half-wave owns one row per slot (float4/lane -> 512B row,
// full wave -> 1KB contiguous per load inst). 4 rows in flight per
// half-wave (offsets +0,+8,+16,+24; loop stride 32) for ILP.
__global__ __launch_bounds__(THREADS) void som_dist_stage1(
    const float* __restrict__ samples,
    const float* __restrict__ nodes,
    float* __restrict__ cand_val,
    int* __restrict__ cand_idx) {
    const int tid  = threadIdx.x;
    const int lane = tid & 63;
    const int w    = tid >> 6;        // wave 0..3
    const int half = lane >> 5;       // 0/1 within wave
    const int l2   = lane & 31;       // lane within half

    const f32x4 s = ((const f32x4*)samples)[l2];

    // chunk per block, rounded to 32 so steady-state iters have no guards
    const int npb   = (((N_NODES + BLOCKS1 - 1) / BLOCKS1) + 31) & ~31;
    const int start = blockIdx.x * npb;
    const int end   = min(start + npb, N_NODES);

    float bv[TOPK];
    int   bi[TOPK];
#pragma unroll
    for (int j = 0; j < TOPK; ++j) { bv[j] = INFINITY; bi[j] = 0x7fffffff; }

    const bool owner = (l2 == 0);

    for (int base = start + w * 2 + half; base < end; base += 32) {
        const int nA = base, nB = base + 8, nC = base + 16, nD = base + 24;
        const bool vB = (nB < end), vC = (nC < end), vD = (nD < end);

        const f32x4 xA = __builtin_nontemporal_load(
            (const f32x4*)(nodes + (size_t)nA * DIM) + l2);
        f32x4 xB = {0.f, 0.f, 0.f, 0.f}, xC = xB, xD = xB;
        if (vB) xB = __builtin_nontemporal_load(
            (const f32x4*)(nodes + (size_t)nB * DIM) + l2);
        if (vC) xC = __builtin_nontemporal_load(
            (const f32x4*)(nodes + (size_t)nC * DIM) + l2);
        if (vD) xD = __builtin_nontemporal_load(
            (const f32x4*)(nodes + (size_t)nD * DIM) + l2);

        float aA = rowdist2(xA, s);
        float aB = rowdist2(xB, s);
        float aC = rowdist2(xC, s);
        float aD = rowdist2(xD, s);

#pragma unroll
        for (int m = 1; m <= 16; m <<= 1) {
            aA += __shfl_xor(aA, m, 64);
            aB += __shfl_xor(aB, m, 64);
            aC += __shfl_xor(aC, m, 64);
            aD += __shfl_xor(aD, m, 64);
        }
        if (owner) {
            insert16(bv, bi, aA, nA);
            if (vB) insert16(bv, bi, aB, nB);
            if (vC) insert16(bv, bi, aC, nC);
            if (vD) insert16(bv, bi, aD, nD);
        }
    }

    // Block merge: 8 owner lists (lanes 0/32 of 4 waves) -> LDS -> thread 0.
    __shared__ float lv[8 * TOPK];
    __shared__ int   li[8 * TOPK];
    const int oid = tid >> 5;  // 0..7
    if (owner) {
#pragma unroll
        for (int j = 0; j < TOPK; ++j) {
            lv[oid * TOPK + j] = bv[j];
            li[oid * TOPK + j] = bi[j];
        }
    }
    __syncthreads();
    if (tid == 0) {
        float rv[TOPK];
        int   ri[TOPK];
#pragma unroll
        for (int j = 0; j < TOPK; ++j) { rv[j] = INFINITY; ri[j] = 0x7fffffff; }
        for (int c = 0; c < 8 * TOPK; ++c) insert16(rv, ri, lv[c], li[c]);
#pragma unroll
        for (int j = 0; j < TOPK; ++j) {
            cand_val[blockIdx.x * TOPK + j] = rv[j];
            cand_idx[blockIdx.x * TOPK + j] = ri[j];
        }
    }
}

// Stage 2: single block merges 16384 candidates -> global top-16, sqrt, emit.
__global__ __launch_bounds__(THREADS) void som_topk_final(
    const float* __restrict__ cand_val,
    const int* __restrict__ cand_idx,
    float* __restrict__ out) {
    const int tid = threadIdx.x;

    float bv[TOPK];
    int   bi[TOPK];
#pragma unroll
    for (int j = 0; j < TOPK; ++j) { bv[j] = INFINITY; bi[j] = 0x7fffffff; }
    for (int c = tid; c < NCAND; c += THREADS)
        insert16(bv, bi, cand_val[c], cand_idx[c]);

    __shared__ float wv[4];
    __shared__ int   wi[4], wt[4];
    __shared__ float s_resv[TOPK];
    __shared__ int   s_resi[TOPK];
    __shared__ int   s_wtid;

    for (int r = 0; r < TOPK; ++r) {
        float v = bv[0];
        int   i = bi[0];
        int   t = tid;
#pragma unroll
        for (int m = 1; m <= 32; m <<= 1) {
            const float ov = __shfl_xor(v, m, 64);
            const int   oi = __shfl_xor(i, m, 64);
            const int   ot = __shfl_xor(t, m, 64);
            if (lexless(ov, oi, v, i)) { v = ov; i = oi; t = ot; }
        }
        if ((tid & 63) == 0) {
            wv[tid >> 6] = v; wi[tid >> 6] = i; wt[tid >> 6] = t;
        }
        __syncthreads();
        if (tid == 0) {
            float bvv = wv[0]; int bii = wi[0]; int btt = wt[0];
            for (int q = 1; q < 4; ++q)
                if (lexless(wv[q], wi[q], bvv, bii)) {
                    bvv = wv[q]; bii = wi[q]; btt = wt[q];
                }
            s_resv[r] = bvv; s_resi[r] = bii; s_wtid = btt;
        }
        __syncthreads();
        if (tid == s_wtid) {
#pragma unroll
            for (int j = 0; j < TOPK - 1; ++j) { bv[j] = bv[j + 1]; bi[j] = bi[j + 1]; }
            bv[TOPK - 1] = INFINITY; bi[TOPK - 1] = 0x7fffffff;
        }
        __syncthreads();
    }

    if (tid < TOPK) {
        out[tid]        = (float)s_resi[tid];   // indices, ascending distance
        out[TOPK + tid] = sqrtf(s_resv[tid]);   // distances
    }
}

extern "C" void kernel_launch(void* const* d_in, const int* in_sizes, int n_in,
                              void* d_out, int out_size, void* d_ws, size_t ws_size,
                              hipStream_t stream) {
    const float* samples = (const float*)d_in[0];
    const float* nodes   = (const float*)d_in[1];
    float* out = (float*)d_out;

    float* cand_val = (float*)d_ws;
    int*   cand_idx = (int*)((char*)d_ws + NCAND * sizeof(float));

    som_dist_stage1<<<BLOCKS1, THREADS, 0, stream>>>(samples, nodes, cand_val, cand_idx);
    som_topk_final<<<1, THREADS, 0, stream>>>(cand_val, cand_idx, out);
}